// Round 1
// baseline (373.869 us; speedup 1.0000x reference)
//
#include <hip/hip_runtime.h>
#include <hip/hip_bf16.h>

// ---------------------------------------------------------------------------
// DRRGHead: 1x1 conv (memory-bound) + 4-layer GraphConv GCN (MFMA bf16 GEMMs)
//           + knn gather + tiny MLP classifier.
// Shapes: inputs (4,32,512,512); node_feats (512,41,576); A (512,41,41);
//         M = 512*41 = 20992 = 164*128 exactly. K divisible by 32, N by 64.
// ---------------------------------------------------------------------------

using f32x4 = __attribute__((ext_vector_type(4))) float;
using s16x8 = __attribute__((ext_vector_type(8))) short;   // 8 bf16 (4 VGPRs)

#define GN 20992          // G*N rows
#define NFEAT 576
#define NGRAPH 512
#define NNODE 41

// ---------------- 1x1 conv: out[b,o,hw] = sum_c in[b,c,hw]*w[o,c] + b[o] ----
__global__ __launch_bounds__(256) void conv1x1_kernel(
    const float* __restrict__ in, const float* __restrict__ w,
    const float* __restrict__ bias, float* __restrict__ out) {
  int p = blockIdx.x * 256 + threadIdx.x;   // float4 index, 4 imgs * 65536
  int img = p >> 16;
  int q = p & 65535;
  const float4* ip = (const float4*)in + (size_t)img * 32 * 65536 + q;
  float4 acc[6];
#pragma unroll
  for (int o = 0; o < 6; ++o) { float b0 = bias[o]; acc[o] = make_float4(b0, b0, b0, b0); }
#pragma unroll 4
  for (int c = 0; c < 32; ++c) {
    float4 x = ip[(size_t)c * 65536];
#pragma unroll
    for (int o = 0; o < 6; ++o) {
      float wv = w[o * 32 + c];
      acc[o].x += x.x * wv; acc[o].y += x.y * wv;
      acc[o].z += x.z * wv; acc[o].w += x.w * wv;
    }
  }
  float4* op = (float4*)out + (size_t)img * 6 * 65536 + q;
#pragma unroll
  for (int o = 0; o < 6; ++o) op[(size_t)o * 65536] = acc[o];
}

// ---------------- weight transpose + cast: W[K][N] f32 -> Wt[N][K] bf16 -----
__global__ void wt_kernel(const float* __restrict__ W, __hip_bfloat16* __restrict__ Wt,
                          int K, int N) {
  int idx = blockIdx.x * 256 + threadIdx.x;
  if (idx >= K * N) return;
  int n = idx % N, k = idx / N;
  Wt[(size_t)n * K + k] = __float2bfloat16(W[idx]);
}

// ---------------- BN stats: deterministic two-stage column reduction --------
__global__ __launch_bounds__(576) void bn_stats_kernel(
    const float* __restrict__ nf, float* __restrict__ partial) {
  int f = threadIdx.x;          // 0..575
  int rb = blockIdx.x;          // 256 blocks x 82 rows
  int r0 = rb * 82;
  float s = 0.f, s2 = 0.f;
  for (int r = r0; r < r0 + 82; ++r) {
    float v = nf[(size_t)r * NFEAT + f];
    s += v; s2 += v * v;
  }
  partial[(size_t)rb * 1152 + f] = s;
  partial[(size_t)rb * 1152 + 576 + f] = s2;
}

__global__ __launch_bounds__(576) void bn_reduce_kernel(
    const float* __restrict__ partial, float* __restrict__ stats) {
  int t = blockIdx.x * 576 + threadIdx.x;   // 0..1151
  float s = 0.f;
  for (int b = 0; b < 256; ++b) s += partial[(size_t)b * 1152 + t];
  stats[t] = s;
}

// ---------------- BN apply -> bf16 into cat1 x-half (stride 1152) -----------
__global__ __launch_bounds__(576) void bn_apply_kernel(
    const float* __restrict__ nf, const float* __restrict__ stats,
    __hip_bfloat16* __restrict__ buf) {
  int r = blockIdx.x, f = threadIdx.x;
  float m = stats[f] * (1.f / GN);
  float v = stats[576 + f] * (1.f / GN) - m * m;
  float inv = rsqrtf(v + 1e-5f);
  float x = nf[(size_t)r * NFEAT + f];
  buf[(size_t)r * 1152 + f] = __float2bfloat16((x - m) * inv);
}

// ---------------- mean aggregation: agg[g,n,f] = sum_m A[g,n,m] x[g,m,f] ----
// buf rows have stride 2*FIN: x in cols [0,FIN), agg written to [FIN,2FIN).
template <int FIN>
__global__ __launch_bounds__(256) void agg_kernel(
    __hip_bfloat16* __restrict__ buf, const float* __restrict__ Aadj) {
  constexpr int STR = 2 * FIN;
  __shared__ float Ash[NNODE * NNODE];
  int g = blockIdx.x;
  for (int i = threadIdx.x; i < NNODE * NNODE; i += 256)
    Ash[i] = Aadj[(size_t)g * (NNODE * NNODE) + i];
  __syncthreads();
  __hip_bfloat16* xg = buf + (size_t)g * NNODE * STR;
  for (int f = threadIdx.x; f < FIN; f += 256) {
    float xr[NNODE];
#pragma unroll
    for (int m = 0; m < NNODE; ++m) xr[m] = __bfloat162float(xg[m * STR + f]);
#pragma unroll 1
    for (int n = 0; n < NNODE; ++n) {
      float a = 0.f;
#pragma unroll
      for (int m = 0; m < NNODE; ++m) a += Ash[n * NNODE + m] * xr[m];
      xg[n * STR + FIN + f] = __float2bfloat16(a);
    }
  }
}

// ---------------- MFMA bf16 GEMM: Y = relu(cat @ W + b) ---------------------
// cat: M x K bf16 row-major (row stride strideA). Bt: N x K bf16 (transposed W).
// 128 x BN tile, 4 waves (2x2), per-wave 64 x (BN/2) = 4 x WNF fragments.
template <int BN, typename OutT>
__global__ __launch_bounds__(256) void gemm_kernel(
    const __hip_bfloat16* __restrict__ Aptr, int strideA,
    const __hip_bfloat16* __restrict__ Bt, const float* __restrict__ bias,
    OutT* __restrict__ Cptr, int strideC, int K) {
  constexpr int WNF = BN / 32;           // n-fragments per wave
  __shared__ short Ash[128 * 40];        // 128 x 32, rows padded to 40 (80 B)
  __shared__ short Bsh[BN * 40];
  int tid = threadIdx.x;
  int m0 = blockIdx.x * 128;
  int n0 = blockIdx.y * BN;
  int wave = tid >> 6, lane = tid & 63;
  int wm = wave >> 1, wn = wave & 1;
  int lr = lane & 15, kb = lane >> 4;    // fragment row/col, k-block (8 elems)

  f32x4 acc[4][WNF];
#pragma unroll
  for (int m = 0; m < 4; ++m)
#pragma unroll
    for (int n = 0; n < WNF; ++n) acc[m][n] = (f32x4){0.f, 0.f, 0.f, 0.f};

  const short* Ag = (const short*)Aptr + (size_t)m0 * strideA;
  const short* Bg = (const short*)Bt + (size_t)n0 * K;

  int nkt = K >> 5;
  for (int kt = 0; kt < nkt; ++kt) {
    int k0 = kt * 32;
    __syncthreads();
    // stage A: 128 rows x 32 cols, 16B per thread-chunk
#pragma unroll
    for (int i = 0; i < 2; ++i) {
      int c = tid + i * 256;
      int r = c >> 2, c8 = (c & 3) * 8;
      uint4 v = *(const uint4*)(Ag + (size_t)r * strideA + k0 + c8);
      *(uint4*)&Ash[r * 40 + c8] = v;
    }
    // stage B (already transposed: rows are output-cols)
#pragma unroll
    for (int i = 0; i < BN / 64; ++i) {
      int c = tid + i * 256;
      int r = c >> 2, c8 = (c & 3) * 8;
      uint4 v = *(const uint4*)(Bg + (size_t)r * K + k0 + c8);
      *(uint4*)&Bsh[r * 40 + c8] = v;
    }
    __syncthreads();
    s16x8 af[4], bfr[WNF];
#pragma unroll
    for (int m = 0; m < 4; ++m)
      af[m] = *(const s16x8*)&Ash[(wm * 64 + m * 16 + lr) * 40 + kb * 8];
#pragma unroll
    for (int n = 0; n < WNF; ++n)
      bfr[n] = *(const s16x8*)&Bsh[(wn * (BN / 2) + n * 16 + lr) * 40 + kb * 8];
#pragma unroll
    for (int m = 0; m < 4; ++m)
#pragma unroll
      for (int n = 0; n < WNF; ++n)
        acc[m][n] = __builtin_amdgcn_mfma_f32_16x16x32_bf16(af[m], bfr[n], acc[m][n], 0, 0, 0);
  }

  // epilogue: C row = 4*(lane>>4)+r, col = lane&15 within each 16x16 fragment
  int rbase = (lane >> 4) * 4;
#pragma unroll
  for (int m = 0; m < 4; ++m) {
    int row = m0 + wm * 64 + m * 16 + rbase;
#pragma unroll
    for (int n = 0; n < WNF; ++n) {
      int col = n0 + wn * (BN / 2) + n * 16 + lr;
      float bv = bias[col];
#pragma unroll
      for (int r = 0; r < 4; ++r) {
        float v = acc[m][n][r] + bv;
        v = v > 0.f ? v : 0.f;
        OutT* dst = Cptr + (size_t)(row + r) * strideC + col;
        if constexpr (sizeof(OutT) == 2) *dst = (OutT)__float2bfloat16(v);
        else *dst = (OutT)v;
      }
    }
  }
}

// ---------------- knn gather + MLP classifier -------------------------------
__global__ __launch_bounds__(256) void classifier_kernel(
    const float* __restrict__ y4, const int* __restrict__ knn,
    const float* __restrict__ w1, const float* __restrict__ b1,
    const float* __restrict__ pa, const float* __restrict__ w2,
    const float* __restrict__ b2, float* __restrict__ out) {
  int e = blockIdx.x * 256 + threadIdx.x;   // 0..4095 edges
  if (e >= NGRAPH * 8) return;
  int g = e >> 3;
  int node = knn[e];
  const float* fp = y4 + ((size_t)g * NNODE + node) * 64;
  float fr[64];
#pragma unroll
  for (int d = 0; d < 64; ++d) fr[d] = fp[d];
  float h[32];
#pragma unroll 1
  for (int j = 0; j < 32; ++j) {
    float a = b1[j];
#pragma unroll
    for (int d = 0; d < 64; ++d) a += fr[d] * w1[d * 32 + j];
    h[j] = a >= 0.f ? a : pa[j] * a;
  }
#pragma unroll
  for (int o = 0; o < 2; ++o) {
    float s = b2[o];
#pragma unroll 1
    for (int j = 0; j < 32; ++j) s += h[j] * w2[j * 2 + o];
    out[(size_t)e * 2 + o] = s;
  }
}

// ---------------------------------------------------------------------------
extern "C" void kernel_launch(void* const* d_in, const int* in_sizes, int n_in,
                              void* d_out, int out_size, void* d_ws, size_t ws_size,
                              hipStream_t stream) {
  const float* inputs     = (const float*)d_in[0];
  const float* node_feats = (const float*)d_in[1];
  const float* Aadj       = (const float*)d_in[2];
  const int*   knn        = (const int*)d_in[3];
  const float* conv_w     = (const float*)d_in[4];
  const float* conv_b     = (const float*)d_in[5];
  const float* W1 = (const float*)d_in[6];  const float* b1 = (const float*)d_in[7];
  const float* W2 = (const float*)d_in[8];  const float* b2 = (const float*)d_in[9];
  const float* W3 = (const float*)d_in[10]; const float* b3 = (const float*)d_in[11];
  const float* W4 = (const float*)d_in[12]; const float* b4 = (const float*)d_in[13];
  const float* cls_w1 = (const float*)d_in[14]; const float* cls_b1 = (const float*)d_in[15];
  const float* prelu_a = (const float*)d_in[16];
  const float* cls_w2 = (const float*)d_in[17]; const float* cls_b2 = (const float*)d_in[18];
  float* out = (float*)d_out;

  // workspace layout (bytes)
  char* ws = (char*)d_ws;
  __hip_bfloat16* bufA = (__hip_bfloat16*)(ws + 0);                 // 20992x1152 bf16 (cat1 / cat3)
  __hip_bfloat16* bufB = (__hip_bfloat16*)(ws + 48365568);          // 20992x1024 bf16 (cat2 / cat4)
  float*          y4   = (float*)(ws + 48365568 + 42991616);        // 20992x64 f32
  char* wp = ws + 48365568 + 42991616 + 5373952;
  __hip_bfloat16* W1t = (__hip_bfloat16*)wp;            wp += 1179648;
  __hip_bfloat16* W2t = (__hip_bfloat16*)wp;            wp += 524288;
  __hip_bfloat16* W3t = (__hip_bfloat16*)wp;            wp += 131072;
  __hip_bfloat16* W4t = (__hip_bfloat16*)wp;            wp += 32768;
  float* partial = (float*)wp;                          wp += 256 * 1152 * 4;
  float* stats   = (float*)wp;                          wp += 1152 * 4;

  // 1x1 conv (independent of GCN)
  conv1x1_kernel<<<1024, 256, 0, stream>>>(inputs, conv_w, conv_b, out);

  // weight transposes to bf16 [N][K]
  wt_kernel<<<(1152 * 512 + 255) / 256, 256, 0, stream>>>(W1, W1t, 1152, 512);
  wt_kernel<<<(1024 * 256 + 255) / 256, 256, 0, stream>>>(W2, W2t, 1024, 256);
  wt_kernel<<<(512 * 128 + 255) / 256, 256, 0, stream>>>(W3, W3t, 512, 128);
  wt_kernel<<<(256 * 64 + 255) / 256, 256, 0, stream>>>(W4, W4t, 256, 64);

  // BatchNorm (training-mode batch stats, biased var)
  bn_stats_kernel<<<256, 576, 0, stream>>>(node_feats, partial);
  bn_reduce_kernel<<<2, 576, 0, stream>>>(partial, stats);
  bn_apply_kernel<<<GN, 576, 0, stream>>>(node_feats, stats, bufA);

  // Layer 1: cat1(20992x1152) @ W1 -> cat2 x-half (stride 1024)
  agg_kernel<576><<<NGRAPH, 256, 0, stream>>>(bufA, Aadj);
  gemm_kernel<128, __hip_bfloat16><<<dim3(164, 4), 256, 0, stream>>>(
      bufA, 1152, W1t, b1, bufB, 1024, 1152);

  // Layer 2: cat2(20992x1024) @ W2 -> cat3 x-half (stride 512, in bufA)
  agg_kernel<512><<<NGRAPH, 256, 0, stream>>>(bufB, Aadj);
  gemm_kernel<128, __hip_bfloat16><<<dim3(164, 2), 256, 0, stream>>>(
      bufB, 1024, W2t, b2, bufA, 512, 1024);

  // Layer 3: cat3(20992x512) @ W3 -> cat4 x-half (stride 256, in bufB)
  agg_kernel<256><<<NGRAPH, 256, 0, stream>>>(bufA, Aadj);
  gemm_kernel<128, __hip_bfloat16><<<dim3(164, 1), 256, 0, stream>>>(
      bufA, 512, W3t, b3, bufB, 256, 512);

  // Layer 4: cat4(20992x256) @ W4 -> y4 f32 (stride 64)
  agg_kernel<128><<<NGRAPH, 256, 0, stream>>>(bufB, Aadj);
  gemm_kernel<64, float><<<dim3(164, 1), 256, 0, stream>>>(
      bufB, 256, W4t, b4, y4, 64, 256);

  // knn gather + classifier -> gcn_pred at d_out[6291456:]
  classifier_kernel<<<16, 256, 0, stream>>>(y4, knn, cls_w1, cls_b1, prelu_a,
                                            cls_w2, cls_b2, out + 6291456);
}

// Round 2
// 349.859 us; speedup vs baseline: 1.0686x; 1.0686x over previous
//
#include <hip/hip_runtime.h>
#include <hip/hip_bf16.h>

// ---------------------------------------------------------------------------
// DRRGHead restructured:
//   relu(cat(x, A@x) @ W + b)  ==  relu(x@W_top + b  +  A @ (x@W_bot))
// so each layer = one MFMA GEMM  P = x @ [W_top | W_bot]  (bias on left half)
// followed by a fused agg-epilogue  y = relu(P_L + A @ P_R).
// GEMM uses m97 structure: 128x128 tile, linear LDS, global_load_lds width=16.
// ---------------------------------------------------------------------------

using f32x4 = __attribute__((ext_vector_type(4))) float;
using s16x8 = __attribute__((ext_vector_type(8))) short;   // 8 bf16

#define GN 20992          // G*N rows (= 164*128 exactly)
#define NFEAT 576
#define NGRAPH 512
#define NNODE 41

typedef __attribute__((address_space(1))) const unsigned int gas_u32;
typedef __attribute__((address_space(3))) unsigned int las_u32;

__device__ __forceinline__ void gl_lds16(const void* g, void* l) {
  __builtin_amdgcn_global_load_lds((gas_u32*)g, (las_u32*)l, 16, 0, 0);
}

// ---------------- 1x1 conv: out[b,o,hw] = sum_c in[b,c,hw]*w[o,c] + b[o] ----
__global__ __launch_bounds__(256) void conv1x1_kernel(
    const float* __restrict__ in, const float* __restrict__ w,
    const float* __restrict__ bias, float* __restrict__ out) {
  int p = blockIdx.x * 256 + threadIdx.x;   // float4 index, 4 imgs * 65536
  int img = p >> 16;
  int q = p & 65535;
  const float4* ip = (const float4*)in + (size_t)img * 32 * 65536 + q;
  float4 acc[6];
#pragma unroll
  for (int o = 0; o < 6; ++o) { float b0 = bias[o]; acc[o] = make_float4(b0, b0, b0, b0); }
#pragma unroll 4
  for (int c = 0; c < 32; ++c) {
    float4 x = ip[(size_t)c * 65536];
#pragma unroll
    for (int o = 0; o < 6; ++o) {
      float wv = w[o * 32 + c];
      acc[o].x += x.x * wv; acc[o].y += x.y * wv;
      acc[o].z += x.z * wv; acc[o].w += x.w * wv;
    }
  }
  float4* op = (float4*)out + (size_t)img * 6 * 65536 + q;
#pragma unroll
  for (int o = 0; o < 6; ++o) op[(size_t)o * 65536] = acc[o];
}

// ---------------- combined weight repack: W(2K x N) f32 -> Bt(2N x K) bf16 --
// Bt[j][k] = j<N ? W[k][j] : W[k+K][j-N]
__device__ __forceinline__ void wt_one(const float* __restrict__ W,
                                       __hip_bfloat16* __restrict__ Bt,
                                       int t, int K, int N) {
  int j = t / K, k = t - j * K;
  float v = (j < N) ? W[(size_t)k * N + j] : W[(size_t)(k + K) * N + (j - N)];
  Bt[(size_t)j * K + k] = __float2bfloat16(v);
}

__global__ __launch_bounds__(256) void wtall_kernel(
    const float* __restrict__ W1, const float* __restrict__ W2,
    const float* __restrict__ W3, const float* __restrict__ W4,
    __hip_bfloat16* __restrict__ B1, __hip_bfloat16* __restrict__ B2,
    __hip_bfloat16* __restrict__ B3, __hip_bfloat16* __restrict__ B4) {
  int t = blockIdx.x * 256 + threadIdx.x;
  // ranges: L1 1024*576=589824, L2 512*512=262144, L3 256*256=65536, L4 128*128=16384
  if (t < 589824) { wt_one(W1, B1, t, 576, 512); return; }
  t -= 589824;
  if (t < 262144) { wt_one(W2, B2, t, 512, 256); return; }
  t -= 262144;
  if (t < 65536) { wt_one(W3, B3, t, 256, 128); return; }
  t -= 65536;
  if (t < 16384) { wt_one(W4, B4, t, 128, 64); return; }
}

// ---------------- BN stats: deterministic two-stage column reduction --------
__global__ __launch_bounds__(576) void bn_stats_kernel(
    const float* __restrict__ nf, float* __restrict__ partial) {
  int f = threadIdx.x;          // 0..575
  int rb = blockIdx.x;          // 256 blocks x 82 rows
  int r0 = rb * 82;
  float s = 0.f, s2 = 0.f;
  for (int r = r0; r < r0 + 82; ++r) {
    float v = nf[(size_t)r * NFEAT + f];
    s += v; s2 += v * v;
  }
  partial[(size_t)rb * 1152 + f] = s;
  partial[(size_t)rb * 1152 + 576 + f] = s2;
}

__global__ __launch_bounds__(576) void bn_reduce_kernel(
    const float* __restrict__ partial, float* __restrict__ stats) {
  int f = threadIdx.x;   // 0..575
  float s = 0.f, s2 = 0.f;
  for (int b = 0; b < 256; ++b) {
    s += partial[(size_t)b * 1152 + f];
    s2 += partial[(size_t)b * 1152 + 576 + f];
  }
  float m = s * (1.f / GN);
  float v = s2 * (1.f / GN) - m * m;
  stats[f] = m;
  stats[576 + f] = rsqrtf(v + 1e-5f);
}

// ---------------- BN apply -> bf16 x0 (contiguous 20992 x 576) --------------
__global__ __launch_bounds__(256) void bn_apply_kernel(
    const float* __restrict__ nf, const float* __restrict__ stats,
    __hip_bfloat16* __restrict__ x0) {
  int idx = blockIdx.x * 256 + threadIdx.x;   // chunk of 8 feats; grid 5904 exact
  int f0 = (idx * 8) % NFEAT;                 // 576 % 8 == 0: never crosses rows
  const float* src = nf + (size_t)idx * 8;
  float4 a = *(const float4*)src, b = *(const float4*)(src + 4);
  float vv[8] = {a.x, a.y, a.z, a.w, b.x, b.y, b.z, b.w};
  __hip_bfloat16 o[8];
#pragma unroll
  for (int j = 0; j < 8; ++j) {
    float m = stats[f0 + j], inv = stats[576 + f0 + j];
    o[j] = __float2bfloat16((vv[j] - m) * inv);
  }
  *(uint4*)&x0[(size_t)idx * 8] = *(const uint4*)o;
}

// ---------------- MFMA bf16 GEMM: P = x @ Bt^T (+bias on cols < biasN) ------
// x: M x K bf16 (row stride K). Bt: N' x K bf16. P: M x N' bf16, NO relu.
// 128x128 tile, 4 waves 2x2, per-wave 64x64 (4x4 fragments of 16x16x32).
// Linear LDS (128 rows x 32 cols), staged via global_load_lds width 16.
__global__ __launch_bounds__(256) void gemm_kernel(
    const __hip_bfloat16* __restrict__ Xptr, const __hip_bfloat16* __restrict__ Bt,
    const float* __restrict__ bias, int biasN,
    __hip_bfloat16* __restrict__ Pptr, int Np, int K) {
  __shared__ short Ash[128 * 32];
  __shared__ short Bsh[128 * 32];
  int tid = threadIdx.x;
  int m0 = blockIdx.x * 128;
  int n0 = blockIdx.y * 128;
  int wave = tid >> 6, lane = tid & 63;
  int wm = wave >> 1, wn = wave & 1;
  int lr = lane & 15, kb = lane >> 4;

  f32x4 acc[4][4];
#pragma unroll
  for (int m = 0; m < 4; ++m)
#pragma unroll
    for (int n = 0; n < 4; ++n) acc[m][n] = (f32x4){0.f, 0.f, 0.f, 0.f};

  const short* Ag = (const short*)Xptr + (size_t)m0 * K;
  const short* Bg = (const short*)Bt + (size_t)n0 * K;

  // staging chunks: c covers 512 x 16B; row = c>>2, col8 = (c&3)*8 shorts
  int c0 = tid, c1 = tid + 256;
  int ar0 = c0 >> 2, ac0 = (c0 & 3) * 8;
  int ar1 = c1 >> 2, ac1 = (c1 & 3) * 8;

  int nkt = K >> 5;
  for (int kt = 0; kt < nkt; ++kt) {
    int k0 = kt * 32;
    __syncthreads();
    gl_lds16(Ag + (size_t)ar0 * K + k0 + ac0, &Ash[c0 * 8]);
    gl_lds16(Ag + (size_t)ar1 * K + k0 + ac1, &Ash[c1 * 8]);
    gl_lds16(Bg + (size_t)ar0 * K + k0 + ac0, &Bsh[c0 * 8]);
    gl_lds16(Bg + (size_t)ar1 * K + k0 + ac1, &Bsh[c1 * 8]);
    __syncthreads();   // compiler drains vmcnt before barrier -> LDS ready
    s16x8 af[4], bfr[4];
#pragma unroll
    for (int m = 0; m < 4; ++m)
      af[m] = *(const s16x8*)&Ash[(wm * 64 + m * 16 + lr) * 32 + kb * 8];
#pragma unroll
    for (int n = 0; n < 4; ++n)
      bfr[n] = *(const s16x8*)&Bsh[(wn * 64 + n * 16 + lr) * 32 + kb * 8];
#pragma unroll
    for (int m = 0; m < 4; ++m)
#pragma unroll
      for (int n = 0; n < 4; ++n)
        acc[m][n] = __builtin_amdgcn_mfma_f32_16x16x32_bf16(af[m], bfr[n], acc[m][n], 0, 0, 0);
  }

  // epilogue: row = 4*(lane>>4)+reg, col = lane&15 within each 16x16 fragment
  int rbase = (lane >> 4) * 4;
#pragma unroll
  for (int m = 0; m < 4; ++m) {
    int row = m0 + wm * 64 + m * 16 + rbase;
#pragma unroll
    for (int n = 0; n < 4; ++n) {
      int col = n0 + wn * 64 + n * 16 + lr;
      float bv = (col < biasN) ? bias[col] : 0.f;
#pragma unroll
      for (int r = 0; r < 4; ++r) {
        float v = acc[m][n][r] + bv;
        Pptr[(size_t)(row + r) * Np + col] = __float2bfloat16(v);
      }
    }
  }
}

// ---------------- fused agg epilogue: y = relu(P_L + A @ P_R) ---------------
// P: M x 2N bf16; y: M x N (bf16 or f32), contiguous stride N.
template <int N, typename OutT>
__global__ __launch_bounds__(256) void aggep_kernel(
    const __hip_bfloat16* __restrict__ P, const float* __restrict__ Aadj,
    OutT* __restrict__ Y) {
  constexpr int GPB = (N >= 256) ? 1 : (256 / N);   // graphs per block
  __shared__ float Ash[GPB * NNODE * NNODE];
  int g0 = blockIdx.x * GPB;
  for (int i = threadIdx.x; i < GPB * NNODE * NNODE; i += 256)
    Ash[i] = Aadj[(size_t)g0 * (NNODE * NNODE) + i];
  __syncthreads();

  int sub, c;
  if constexpr (GPB == 1) { sub = 0; c = threadIdx.x; }
  else { sub = threadIdx.x / N; c = threadIdx.x % N; }
  const float* Am = &Ash[sub * NNODE * NNODE];
  const __hip_bfloat16* Pg = P + (size_t)(g0 + sub) * NNODE * (2 * N);
  OutT* Yg = Y + (size_t)(g0 + sub) * NNODE * N;

  for (; c < N; c += 256) {   // GPB==1: loops; GPB>1: single pass
    float pr[NNODE];
#pragma unroll
    for (int m = 0; m < NNODE; ++m)
      pr[m] = __bfloat162float(Pg[(size_t)m * (2 * N) + N + c]);
#pragma unroll 1
    for (int n = 0; n < NNODE; ++n) {
      float a = __bfloat162float(Pg[(size_t)n * (2 * N) + c]);
#pragma unroll
      for (int m = 0; m < NNODE; ++m) a += Am[n * NNODE + m] * pr[m];
      a = a > 0.f ? a : 0.f;
      if constexpr (sizeof(OutT) == 2) Yg[(size_t)n * N + c] = __float2bfloat16(a);
      else Yg[(size_t)n * N + c] = a;
    }
    if constexpr (GPB > 1) break;
  }
}

// ---------------- knn gather + MLP classifier -------------------------------
__global__ __launch_bounds__(256) void classifier_kernel(
    const float* __restrict__ y4, const int* __restrict__ knn,
    const float* __restrict__ w1, const float* __restrict__ b1,
    const float* __restrict__ pa, const float* __restrict__ w2,
    const float* __restrict__ b2, float* __restrict__ out) {
  int e = blockIdx.x * 256 + threadIdx.x;   // 0..4095 edges
  if (e >= NGRAPH * 8) return;
  int g = e >> 3;
  int node = knn[e];
  const float* fp = y4 + ((size_t)g * NNODE + node) * 64;
  float fr[64];
#pragma unroll
  for (int d = 0; d < 64; ++d) fr[d] = fp[d];
  float h[32];
#pragma unroll 1
  for (int j = 0; j < 32; ++j) {
    float a = b1[j];
#pragma unroll
    for (int d = 0; d < 64; ++d) a += fr[d] * w1[d * 32 + j];
    h[j] = a >= 0.f ? a : pa[j] * a;
  }
#pragma unroll
  for (int o = 0; o < 2; ++o) {
    float s = b2[o];
#pragma unroll 1
    for (int j = 0; j < 32; ++j) s += h[j] * w2[j * 2 + o];
    out[(size_t)e * 2 + o] = s;
  }
}

// ---------------------------------------------------------------------------
extern "C" void kernel_launch(void* const* d_in, const int* in_sizes, int n_in,
                              void* d_out, int out_size, void* d_ws, size_t ws_size,
                              hipStream_t stream) {
  const float* inputs     = (const float*)d_in[0];
  const float* node_feats = (const float*)d_in[1];
  const float* Aadj       = (const float*)d_in[2];
  const int*   knn        = (const int*)d_in[3];
  const float* conv_w     = (const float*)d_in[4];
  const float* conv_b     = (const float*)d_in[5];
  const float* W1 = (const float*)d_in[6];  const float* b1 = (const float*)d_in[7];
  const float* W2 = (const float*)d_in[8];  const float* b2 = (const float*)d_in[9];
  const float* W3 = (const float*)d_in[10]; const float* b3 = (const float*)d_in[11];
  const float* W4 = (const float*)d_in[12]; const float* b4 = (const float*)d_in[13];
  const float* cls_w1 = (const float*)d_in[14]; const float* cls_b1 = (const float*)d_in[15];
  const float* prelu_a = (const float*)d_in[16];
  const float* cls_w2 = (const float*)d_in[17]; const float* cls_b2 = (const float*)d_in[18];
  float* out = (float*)d_out;

  // workspace layout (bytes): two ping-pong regions + weights + stats
  char* ws = (char*)d_ws;
  // R1: x0(24.18MB) / x1(21.5) / x2(10.7) / x3(5.4) / y4(5.4 f32)
  char* R1 = ws;
  // R2: P1(43.0MB) / P2(21.5) / P3(10.7) / P4(5.4)
  char* R2 = ws + 24200192;
  char* wp = ws + 24200192 + 42991616;
  __hip_bfloat16* B1t = (__hip_bfloat16*)wp;  wp += 1179648;   // 1024 x 576
  __hip_bfloat16* B2t = (__hip_bfloat16*)wp;  wp += 524288;    // 512 x 512
  __hip_bfloat16* B3t = (__hip_bfloat16*)wp;  wp += 131072;    // 256 x 256
  __hip_bfloat16* B4t = (__hip_bfloat16*)wp;  wp += 32768;     // 128 x 128
  float* partial = (float*)wp;                wp += 256 * 1152 * 4;
  float* stats   = (float*)wp;                wp += 1152 * 4;

  __hip_bfloat16* x0 = (__hip_bfloat16*)R1;
  __hip_bfloat16* P1 = (__hip_bfloat16*)R2;

  // 1x1 conv (independent)
  conv1x1_kernel<<<1024, 256, 0, stream>>>(inputs, conv_w, conv_b, out);

  // combined weight repack (total 933,888 elems)
  wtall_kernel<<<3648, 256, 0, stream>>>(W1, W2, W3, W4, B1t, B2t, B3t, B4t);

  // BatchNorm
  bn_stats_kernel<<<256, 576, 0, stream>>>(node_feats, partial);
  bn_reduce_kernel<<<1, 576, 0, stream>>>(partial, stats);
  bn_apply_kernel<<<5904, 256, 0, stream>>>(node_feats, stats, x0);

  // Layer 1: P1 = x0(20992x576) @ B1t(1024x576)^T ; y1 = relu(P_L + A@P_R)
  gemm_kernel<<<dim3(164, 8), 256, 0, stream>>>(x0, B1t, b1, 512, P1, 1024, 576);
  aggep_kernel<512, __hip_bfloat16><<<512, 256, 0, stream>>>(
      P1, Aadj, (__hip_bfloat16*)R1);

  // Layer 2: K=512, N'=512
  gemm_kernel<<<dim3(164, 4), 256, 0, stream>>>(
      (__hip_bfloat16*)R1, B2t, b2, 256, (__hip_bfloat16*)R2, 512, 512);
  aggep_kernel<256, __hip_bfloat16><<<512, 256, 0, stream>>>(
      (__hip_bfloat16*)R2, Aadj, (__hip_bfloat16*)R1);

  // Layer 3: K=256, N'=256
  gemm_kernel<<<dim3(164, 2), 256, 0, stream>>>(
      (__hip_bfloat16*)R1, B3t, b3, 128, (__hip_bfloat16*)R2, 256, 256);
  aggep_kernel<128, __hip_bfloat16><<<256, 256, 0, stream>>>(
      (__hip_bfloat16*)R2, Aadj, (__hip_bfloat16*)R1);

  // Layer 4: K=128, N'=128 -> y4 f32
  gemm_kernel<<<dim3(164, 1), 256, 0, stream>>>(
      (__hip_bfloat16*)R1, B4t, b4, 64, (__hip_bfloat16*)R2, 128, 128);
  aggep_kernel<64, float><<<128, 256, 0, stream>>>(
      (__hip_bfloat16*)R2, Aadj, (float*)R1);

  // knn gather + classifier -> gcn_pred at d_out[6291456:]
  classifier_kernel<<<16, 256, 0, stream>>>((float*)R1, knn, cls_w1, cls_b1,
                                            prelu_a, cls_w2, cls_b2, out + 6291456);
}

// Round 3
// 323.382 us; speedup vs baseline: 1.1561x; 1.0819x over previous
//
#include <hip/hip_runtime.h>
#include <hip/hip_bf16.h>

// ---------------------------------------------------------------------------
// DRRGHead restructured:
//   relu(cat(x, A@x) @ W + b)  ==  relu(x@W_top + b  +  A @ (x@W_bot))
// Each layer = one MFMA GEMM  P = x @ [W_top | W_bot]  (bias on left half)
// followed by fused agg-epilogue  y = relu(P_L + A @ P_R).
// GEMM: 128x128 tile, 2-phase double-buffered LDS, global_load_lds width=16,
//       XCD-supergroup block swizzle (8 m-tiles round-robin, n-tiles local).
// Layer 4 agg is fused with the knn-gather + MLP classifier (y in LDS only).
// ---------------------------------------------------------------------------

using f32x4 = __attribute__((ext_vector_type(4))) float;
using s16x8 = __attribute__((ext_vector_type(8))) short;   // 8 bf16

#define GN 20992          // G*N rows (= 164*128 exactly)
#define NFEAT 576
#define NGRAPH 512
#define NNODE 41
#define NTM 164           // m-tiles of 128

typedef __attribute__((address_space(1))) const unsigned int gas_u32;
typedef __attribute__((address_space(3))) unsigned int las_u32;

__device__ __forceinline__ void gl_lds16(const void* g, void* l) {
  __builtin_amdgcn_global_load_lds((gas_u32*)g, (las_u32*)l, 16, 0, 0);
}

// ---------------- 1x1 conv: out[b,o,hw] = sum_c in[b,c,hw]*w[o,c] + b[o] ----
__global__ __launch_bounds__(256) void conv1x1_kernel(
    const float* __restrict__ in, const float* __restrict__ w,
    const float* __restrict__ bias, float* __restrict__ out) {
  int p = blockIdx.x * 256 + threadIdx.x;   // float4 index, 4 imgs * 65536
  int img = p >> 16;
  int q = p & 65535;
  const float4* ip = (const float4*)in + (size_t)img * 32 * 65536 + q;
  float4 acc[6];
#pragma unroll
  for (int o = 0; o < 6; ++o) { float b0 = bias[o]; acc[o] = make_float4(b0, b0, b0, b0); }
#pragma unroll 4
  for (int c = 0; c < 32; ++c) {
    float4 x = ip[(size_t)c * 65536];
#pragma unroll
    for (int o = 0; o < 6; ++o) {
      float wv = w[o * 32 + c];
      acc[o].x += x.x * wv; acc[o].y += x.y * wv;
      acc[o].z += x.z * wv; acc[o].w += x.w * wv;
    }
  }
  float4* op = (float4*)out + (size_t)img * 6 * 65536 + q;
#pragma unroll
  for (int o = 0; o < 6; ++o) op[(size_t)o * 65536] = acc[o];
}

// ---------------- LDS-tiled weight repack: W(2K x N) f32 -> Bt(2N x K) bf16 -
// Per 32x32 tile: coalesced read, LDS transpose (+1 pad), coalesced bf16 write.
__global__ __launch_bounds__(256) void wt_kernel(
    const float* __restrict__ W1, const float* __restrict__ W2,
    const float* __restrict__ W3, const float* __restrict__ W4,
    __hip_bfloat16* __restrict__ B1, __hip_bfloat16* __restrict__ B2,
    __hip_bfloat16* __restrict__ B3, __hip_bfloat16* __restrict__ B4) {
  int b = blockIdx.x;
  const float* W; __hip_bfloat16* B; int K, N, t;
  if (b < 576)      { W = W1; B = B1; K = 576; N = 512; t = b; }         // 18*16*2
  else if (b < 832) { W = W2; B = B2; K = 512; N = 256; t = b - 576; }   // 16*8*2
  else if (b < 896) { W = W3; B = B3; K = 256; N = 128; t = b - 832; }   // 8*4*2
  else              { W = W4; B = B4; K = 128; N = 64;  t = b - 896; }   // 4*2*2
  int tilesN = N >> 5;
  int perhalf = (K >> 5) * tilesN;
  int h = t / perhalf; t -= h * perhalf;
  int tk = t / tilesN, tn = t - tk * tilesN;
  __shared__ float T[32][33];
  int r = threadIdx.x >> 5, cc = threadIdx.x & 31;   // 8 rows x 32 cols
  const float* Wh = W + (size_t)h * K * N;
#pragma unroll
  for (int i = 0; i < 4; ++i)
    T[r + i * 8][cc] = Wh[(size_t)(tk * 32 + r + i * 8) * N + tn * 32 + cc];
  __syncthreads();
  __hip_bfloat16* Bh = B + (size_t)h * N * K;
#pragma unroll
  for (int i = 0; i < 4; ++i)
    Bh[(size_t)(tn * 32 + r + i * 8) * K + tk * 32 + cc] =
        __float2bfloat16(T[cc][r + i * 8]);
}

// ---------------- BN stats: deterministic two-stage column reduction --------
__global__ __launch_bounds__(576) void bn_stats_kernel(
    const float* __restrict__ nf, float* __restrict__ partial) {
  int f = threadIdx.x;          // 0..575
  int rb = blockIdx.x;          // 256 blocks x 82 rows
  int r0 = rb * 82;
  float s = 0.f, s2 = 0.f;
  for (int r = r0; r < r0 + 82; ++r) {
    float v = nf[(size_t)r * NFEAT + f];
    s += v; s2 += v * v;
  }
  partial[(size_t)rb * 1152 + f] = s;
  partial[(size_t)rb * 1152 + 576 + f] = s2;
}

__global__ __launch_bounds__(576) void bn_reduce_kernel(
    const float* __restrict__ partial, float* __restrict__ stats) {
  int f = threadIdx.x;   // 0..575
  float s = 0.f, s2 = 0.f;
#pragma unroll 8
  for (int b = 0; b < 256; ++b) {
    s += partial[(size_t)b * 1152 + f];
    s2 += partial[(size_t)b * 1152 + 576 + f];
  }
  float m = s * (1.f / GN);
  float v = s2 * (1.f / GN) - m * m;
  stats[f] = m;
  stats[576 + f] = rsqrtf(v + 1e-5f);
}

// ---------------- BN apply -> bf16 x0 (contiguous 20992 x 576) --------------
__global__ __launch_bounds__(256) void bn_apply_kernel(
    const float* __restrict__ nf, const float* __restrict__ stats,
    __hip_bfloat16* __restrict__ x0) {
  int idx = blockIdx.x * 256 + threadIdx.x;   // chunk of 8 feats; grid 5904 exact
  int f0 = (idx * 8) % NFEAT;                 // 576 % 8 == 0: never crosses rows
  const float* src = nf + (size_t)idx * 8;
  float4 a = *(const float4*)src, b = *(const float4*)(src + 4);
  float vv[8] = {a.x, a.y, a.z, a.w, b.x, b.y, b.z, b.w};
  __hip_bfloat16 o[8];
#pragma unroll
  for (int j = 0; j < 8; ++j) {
    float m = stats[f0 + j], inv = stats[576 + f0 + j];
    o[j] = __float2bfloat16((vv[j] - m) * inv);
  }
  *(uint4*)&x0[(size_t)idx * 8] = *(const uint4*)o;
}

// ---------------- MFMA bf16 GEMM: P = x @ Bt^T (+bias on cols < biasN) ------
// 128x128 tile, 4 waves 2x2, 2-phase double-buffered LDS (BK=32), one barrier
// per K-step. Block swizzle: supergroups of 8 m-tiles; within a supergroup
// dispatch order cycles m-tiles (XCD round-robin) so each XCD walks all
// n-tiles of "its" m-tile with the A-panel L2-resident.
__global__ __launch_bounds__(256) void gemm_kernel(
    const __hip_bfloat16* __restrict__ Xptr, const __hip_bfloat16* __restrict__ Bt,
    const float* __restrict__ bias, int biasN,
    __hip_bfloat16* __restrict__ Pptr, int Np, int K, int NTN) {
  __shared__ short Ash[2][128 * 32];
  __shared__ short Bsh[2][128 * 32];
  int tid = threadIdx.x;

  int bid = blockIdx.x;
  int sg = bid / (NTN * 8);
  int rem = bid - sg * (NTN * 8);
  int Wm = NTM - sg * 8; if (Wm > 8) Wm = 8;
  int mt = sg * 8 + rem % Wm;
  int nt = rem / Wm;
  int m0 = mt * 128, n0 = nt * 128;

  int wave = tid >> 6, lane = tid & 63;
  int wm = wave >> 1, wn = wave & 1;
  int lr = lane & 15, kb = lane >> 4;

  f32x4 acc[4][4];
#pragma unroll
  for (int m = 0; m < 4; ++m)
#pragma unroll
    for (int n = 0; n < 4; ++n) acc[m][n] = (f32x4){0.f, 0.f, 0.f, 0.f};

  const short* Ag = (const short*)Xptr + (size_t)m0 * K;
  const short* Bg = (const short*)Bt + (size_t)n0 * K;

  int c0 = tid, c1 = tid + 256;
  int ar0 = c0 >> 2, ac0 = (c0 & 3) * 8;
  int ar1 = c1 >> 2, ac1 = (c1 & 3) * 8;

  // prologue: stage K-tile 0 into buffer 0
  gl_lds16(Ag + (size_t)ar0 * K + ac0, &Ash[0][c0 * 8]);
  gl_lds16(Ag + (size_t)ar1 * K + ac1, &Ash[0][c1 * 8]);
  gl_lds16(Bg + (size_t)ar0 * K + ac0, &Bsh[0][c0 * 8]);
  gl_lds16(Bg + (size_t)ar1 * K + ac1, &Bsh[0][c1 * 8]);
  __syncthreads();   // drains vmcnt -> tile 0 resident

  int nkt = K >> 5;
  int cur = 0;
  for (int kt = 0; kt < nkt; ++kt) {
    // issue prefetch of next K-tile into the other buffer (overlaps compute)
    if (kt + 1 < nkt) {
      int k1 = (kt + 1) * 32;
      gl_lds16(Ag + (size_t)ar0 * K + k1 + ac0, &Ash[cur ^ 1][c0 * 8]);
      gl_lds16(Ag + (size_t)ar1 * K + k1 + ac1, &Ash[cur ^ 1][c1 * 8]);
      gl_lds16(Bg + (size_t)ar0 * K + k1 + ac0, &Bsh[cur ^ 1][c0 * 8]);
      gl_lds16(Bg + (size_t)ar1 * K + k1 + ac1, &Bsh[cur ^ 1][c1 * 8]);
    }
    s16x8 af[4], bfr[4];
#pragma unroll
    for (int m = 0; m < 4; ++m)
      af[m] = *(const s16x8*)&Ash[cur][(wm * 64 + m * 16 + lr) * 32 + kb * 8];
#pragma unroll
    for (int n = 0; n < 4; ++n)
      bfr[n] = *(const s16x8*)&Bsh[cur][(wn * 64 + n * 16 + lr) * 32 + kb * 8];
#pragma unroll
    for (int m = 0; m < 4; ++m)
#pragma unroll
      for (int n = 0; n < 4; ++n)
        acc[m][n] = __builtin_amdgcn_mfma_f32_16x16x32_bf16(af[m], bfr[n], acc[m][n], 0, 0, 0);
    __syncthreads();   // waits prefetch done + all waves done reading cur
    cur ^= 1;
  }

  // epilogue: row = 4*(lane>>4)+reg, col = lane&15 within each 16x16 fragment
  int rbase = (lane >> 4) * 4;
#pragma unroll
  for (int m = 0; m < 4; ++m) {
    int row = m0 + wm * 64 + m * 16 + rbase;
#pragma unroll
    for (int n = 0; n < 4; ++n) {
      int col = n0 + wn * 64 + n * 16 + lr;
      float bv = (col < biasN) ? bias[col] : 0.f;
#pragma unroll
      for (int r = 0; r < 4; ++r) {
        float v = acc[m][n][r] + bv;
        Pptr[(size_t)(row + r) * Np + col] = __float2bfloat16(v);
      }
    }
  }
}

// ---------------- fused agg epilogue: y = relu(P_L + A @ P_R) ---------------
// P: M x 2N bf16; y: M x N bf16, contiguous stride N. Layers 1-3.
template <int N>
__global__ __launch_bounds__(256) void aggep_kernel(
    const __hip_bfloat16* __restrict__ P, const float* __restrict__ Aadj,
    __hip_bfloat16* __restrict__ Y) {
  constexpr int GPB = (N >= 256) ? 1 : (256 / N);   // graphs per block
  __shared__ float Ash[GPB * NNODE * NNODE];
  int g0 = blockIdx.x * GPB;
  for (int i = threadIdx.x; i < GPB * NNODE * NNODE; i += 256)
    Ash[i] = Aadj[(size_t)g0 * (NNODE * NNODE) + i];
  __syncthreads();

  int sub, c;
  if constexpr (GPB == 1) { sub = 0; c = threadIdx.x; }
  else { sub = threadIdx.x / N; c = threadIdx.x % N; }
  const float* Am = &Ash[sub * NNODE * NNODE];
  const __hip_bfloat16* Pg = P + (size_t)(g0 + sub) * NNODE * (2 * N);
  __hip_bfloat16* Yg = Y + (size_t)(g0 + sub) * NNODE * N;

  for (; c < N; c += 256) {
    float pr[NNODE];
#pragma unroll
    for (int m = 0; m < NNODE; ++m)
      pr[m] = __bfloat162float(Pg[(size_t)m * (2 * N) + N + c]);
#pragma unroll 1
    for (int n = 0; n < NNODE; ++n) {
      float a = __bfloat162float(Pg[(size_t)n * (2 * N) + c]);
#pragma unroll
      for (int m = 0; m < NNODE; ++m) a += Am[n * NNODE + m] * pr[m];
      a = a > 0.f ? a : 0.f;
      Yg[(size_t)n * N + c] = __float2bfloat16(a);
    }
    if constexpr (GPB > 1) break;
  }
}

// ---------------- layer-4 agg + knn gather + MLP classifier (fused) ---------
// P: 20992 x 128 bf16 (L: cols 0-63 with b4 added; R: cols 64-127).
// Block = 4 graphs. y kept in LDS; knn indices are within-graph.
__global__ __launch_bounds__(256) void aggcls_kernel(
    const __hip_bfloat16* __restrict__ P, const float* __restrict__ Aadj,
    const int* __restrict__ knn, const float* __restrict__ w1,
    const float* __restrict__ b1, const float* __restrict__ pa,
    const float* __restrict__ w2, const float* __restrict__ b2,
    float* __restrict__ out) {
  __shared__ float Ash[4 * NNODE * NNODE];   // 26.9 KB
  __shared__ float Ysh[4 * NNODE * 64];      // 42 KB
  __shared__ float Wsh[64 * 32];             // 8 KB
  __shared__ float cb[130];                  // b1(32), pa(32), w2(64), b2(2)
  int tid = threadIdx.x;
  int g0 = blockIdx.x * 4;
  for (int i = tid; i < 4 * NNODE * NNODE; i += 256)
    Ash[i] = Aadj[(size_t)g0 * (NNODE * NNODE) + i];
  for (int i = tid; i < 2048; i += 256) Wsh[i] = w1[i];
  if (tid < 32) { cb[tid] = b1[tid]; cb[32 + tid] = pa[tid]; }
  if (tid < 64) cb[64 + tid] = w2[tid];
  if (tid < 2) cb[128 + tid] = b2[tid];
  __syncthreads();

  int sub = tid >> 6, c = tid & 63;
  const float* Am = &Ash[sub * NNODE * NNODE];
  const __hip_bfloat16* Pg = P + (size_t)(g0 + sub) * NNODE * 128;
  float pr[NNODE];
#pragma unroll
  for (int m = 0; m < NNODE; ++m)
    pr[m] = __bfloat162float(Pg[(size_t)m * 128 + 64 + c]);
#pragma unroll 1
  for (int n = 0; n < NNODE; ++n) {
    float a = __bfloat162float(Pg[(size_t)n * 128 + c]);
#pragma unroll
    for (int m = 0; m < NNODE; ++m) a += Am[n * NNODE + m] * pr[m];
    Ysh[(sub * NNODE + n) * 64 + c] = a > 0.f ? a : 0.f;
  }
  __syncthreads();

  if (tid < 32) {
    int e = g0 * 8 + tid;          // 4 graphs x 8 edges
    int gl = tid >> 3;
    int node = knn[e];
    const float* fp = &Ysh[(gl * NNODE + node) * 64];
    float h[32];
#pragma unroll 1
    for (int j = 0; j < 32; ++j) {
      float a = cb[j];
#pragma unroll
      for (int d = 0; d < 64; ++d) a += fp[d] * Wsh[d * 32 + j];
      h[j] = a >= 0.f ? a : cb[32 + j] * a;
    }
#pragma unroll
    for (int o = 0; o < 2; ++o) {
      float s = cb[128 + o];
#pragma unroll 1
      for (int j = 0; j < 32; ++j) s += h[j] * cb[64 + j * 2 + o];
      out[(size_t)e * 2 + o] = s;
    }
  }
}

// ---------------------------------------------------------------------------
extern "C" void kernel_launch(void* const* d_in, const int* in_sizes, int n_in,
                              void* d_out, int out_size, void* d_ws, size_t ws_size,
                              hipStream_t stream) {
  const float* inputs     = (const float*)d_in[0];
  const float* node_feats = (const float*)d_in[1];
  const float* Aadj       = (const float*)d_in[2];
  const int*   knn        = (const int*)d_in[3];
  const float* conv_w     = (const float*)d_in[4];
  const float* conv_b     = (const float*)d_in[5];
  const float* W1 = (const float*)d_in[6];  const float* b1 = (const float*)d_in[7];
  const float* W2 = (const float*)d_in[8];  const float* b2 = (const float*)d_in[9];
  const float* W3 = (const float*)d_in[10]; const float* b3 = (const float*)d_in[11];
  const float* W4 = (const float*)d_in[12]; const float* b4 = (const float*)d_in[13];
  const float* cls_w1 = (const float*)d_in[14]; const float* cls_b1 = (const float*)d_in[15];
  const float* prelu_a = (const float*)d_in[16];
  const float* cls_w2 = (const float*)d_in[17]; const float* cls_b2 = (const float*)d_in[18];
  float* out = (float*)d_out;

  // workspace layout (bytes): two ping-pong regions + weights + stats
  char* ws = (char*)d_ws;
  char* R1 = ws;                       // x0(24.18MB) / x1 / x2 / x3
  char* R2 = ws + 24200192;            // P1(43.0MB) / P2 / P3 / P4
  char* wp = ws + 24200192 + 42991616;
  __hip_bfloat16* B1t = (__hip_bfloat16*)wp;  wp += 1179648;   // 1024 x 576
  __hip_bfloat16* B2t = (__hip_bfloat16*)wp;  wp += 524288;    // 512 x 512
  __hip_bfloat16* B3t = (__hip_bfloat16*)wp;  wp += 131072;    // 256 x 256
  __hip_bfloat16* B4t = (__hip_bfloat16*)wp;  wp += 32768;     // 128 x 128
  float* partial = (float*)wp;                wp += 256 * 1152 * 4;
  float* stats   = (float*)wp;                wp += 1152 * 4;

  __hip_bfloat16* x0 = (__hip_bfloat16*)R1;
  __hip_bfloat16* P1 = (__hip_bfloat16*)R2;

  // 1x1 conv (independent)
  conv1x1_kernel<<<1024, 256, 0, stream>>>(inputs, conv_w, conv_b, out);

  // weight repack via LDS-tiled transpose (912 tiles total)
  wt_kernel<<<912, 256, 0, stream>>>(W1, W2, W3, W4, B1t, B2t, B3t, B4t);

  // BatchNorm
  bn_stats_kernel<<<256, 576, 0, stream>>>(node_feats, partial);
  bn_reduce_kernel<<<1, 576, 0, stream>>>(partial, stats);
  bn_apply_kernel<<<5904, 256, 0, stream>>>(node_feats, stats, x0);

  // Layer 1: P1 = x0(20992x576) @ B1t(1024x576)^T ; y1 = relu(P_L + A@P_R)
  gemm_kernel<<<NTM * 8, 256, 0, stream>>>(x0, B1t, b1, 512, P1, 1024, 576, 8);
  aggep_kernel<512><<<512, 256, 0, stream>>>(P1, Aadj, (__hip_bfloat16*)R1);

  // Layer 2: K=512, N'=512
  gemm_kernel<<<NTM * 4, 256, 0, stream>>>(
      (__hip_bfloat16*)R1, B2t, b2, 256, (__hip_bfloat16*)R2, 512, 512, 4);
  aggep_kernel<256><<<512, 256, 0, stream>>>(
      (__hip_bfloat16*)R2, Aadj, (__hip_bfloat16*)R1);

  // Layer 3: K=256, N'=256
  gemm_kernel<<<NTM * 2, 256, 0, stream>>>(
      (__hip_bfloat16*)R1, B3t, b3, 128, (__hip_bfloat16*)R2, 256, 256, 2);
  aggep_kernel<128><<<256, 256, 0, stream>>>(
      (__hip_bfloat16*)R2, Aadj, (__hip_bfloat16*)R1);

  // Layer 4: K=128, N'=128
  gemm_kernel<<<NTM * 1, 256, 0, stream>>>(
      (__hip_bfloat16*)R1, B4t, b4, 64, (__hip_bfloat16*)R2, 128, 128, 1);

  // fused layer-4 aggregation + knn gather + classifier
  aggcls_kernel<<<128, 256, 0, stream>>>(
      (__hip_bfloat16*)R2, Aadj, knn, cls_w1, cls_b1, prelu_a, cls_w2, cls_b2,
      out + 6291456);
}